// Round 4
// baseline (173.999 us; speedup 1.0000x reference)
//
#include <hip/hip_runtime.h>
#include <cstdio>
#include <cmath>

#define TSEQ 2048
#define CDIM 1024
#define NBATCH 4

typedef float f32x4 __attribute__((ext_vector_type(4)));
typedef __bf16 bf16x8 __attribute__((ext_vector_type(8)));
typedef unsigned short u16;

// f32 -> bf16 round-to-nearest-even
__device__ __forceinline__ u16 f2bf(float f) {
  unsigned u = __builtin_bit_cast(unsigned, f);
  unsigned r = (u + 0x7FFFu + ((u >> 16) & 1u)) >> 16;
  return (u16)r;
}

// async global->LDS, 16B per lane; lds base wave-uniform (HW adds lane*16)
__device__ __forceinline__ void gload_lds16(const void* g, void* l) {
  __builtin_amdgcn_global_load_lds(
      (__attribute__((address_space(1))) void*)g,
      (__attribute__((address_space(3))) void*)l, 16, 0, 0);
}

// ---------------------------------------------------------------------------
// legacy 128x128 core (still used by scores/pv this round)
// ---------------------------------------------------------------------------
__device__ __forceinline__ void gemm_core_128(
    const u16* __restrict__ A, const u16* __restrict__ B,
    int lda, int ldb, int m0, int n0, int kEnd,
    u16* As, u16* Bs, f32x4 acc[4][4])
{
  const int tid = threadIdx.x;
  const int w = tid >> 6, l = tid & 63;
  const int wr = w >> 1, wc = w & 1;
  const int srow = l >> 2;
  const int scol = (l & 3) * 8;
  const int fr = l & 15;
  const int fk = (l >> 4) * 8;

  for (int k0 = 0; k0 < kEnd; k0 += 32) {
    const u16* ga = A + (size_t)(m0 + w * 16 + srow) * lda + k0 + scol;
    gload_lds16(ga, As + w * 16 * 32);
    gload_lds16(ga + (size_t)64 * lda, As + (64 + w * 16) * 32);
    const u16* gb = B + (size_t)(n0 + w * 16 + srow) * ldb + k0 + scol;
    gload_lds16(gb, Bs + w * 16 * 32);
    gload_lds16(gb + (size_t)64 * ldb, Bs + (64 + w * 16) * 32);
    __syncthreads();

    bf16x8 af[4], bfv[4];
#pragma unroll
    for (int i = 0; i < 4; ++i)
      af[i] = *reinterpret_cast<const bf16x8*>(As + (wr * 64 + i * 16 + fr) * 32 + fk);
#pragma unroll
    for (int i = 0; i < 4; ++i)
      bfv[i] = *reinterpret_cast<const bf16x8*>(Bs + (wc * 64 + i * 16 + fr) * 32 + fk);
#pragma unroll
    for (int m = 0; m < 4; ++m)
#pragma unroll
      for (int n = 0; n < 4; ++n)
        acc[m][n] = __builtin_amdgcn_mfma_f32_16x16x32_bf16(af[m], bfv[n], acc[m][n], 0, 0, 0);
    __syncthreads();
  }
}

#define ACC_ZERO(acc)                                   \
  _Pragma("unroll") for (int m_ = 0; m_ < 4; ++m_)      \
  _Pragma("unroll") for (int n_ = 0; n_ < 4; ++n_)      \
      acc[m_][n_] = (f32x4){0.f, 0.f, 0.f, 0.f};

// ---------------------------------------------------------------------------
// single cvt kernel for x, Wk, Wq, Wv
__global__ void __launch_bounds__(256) k_cvt_all(
    const float* __restrict__ x, const float* __restrict__ Wk,
    const float* __restrict__ Wq, const float* __restrict__ Wv,
    u16* __restrict__ xb, u16* __restrict__ wb)
{
  const int NX4 = (NBATCH * TSEQ * CDIM) / 4;
  const int NW4 = (CDIM * CDIM) / 4;
  int g = blockIdx.x * 256 + threadIdx.x;
  const float* src; u16* dst; int i;
  if (g < NX4) { src = x; dst = xb; i = g; }
  else {
    int g2 = g - NX4;
    int w = g2 / NW4; i = g2 - w * NW4;
    src = (w == 0) ? Wk : (w == 1) ? Wq : Wv;
    dst = wb + (size_t)w * CDIM * CDIM;
  }
  float4 v = ((const float4*)src)[i];
  ushort4 o;
  o.x = f2bf(v.x); o.y = f2bf(v.y); o.z = f2bf(v.z); o.w = f2bf(v.w);
  ((ushort4*)dst)[i] = o;
}

// ---------------------------------------------------------------------------
// 8-phase 256x256 QKV GEMM (m201 template). A = xb [8192][1024],
// B = wb [3072][1024] (K|Q|V weights stacked), both K-major.
// 512 thr = 8 waves (2M x 4N), per-wave C = 128x64. BK=64, NT=16 K-tiles.
// LDS 128KiB: A/B x 2dbuf x 2half x [128][64] bf16, st_16x32 swizzle.
// Half-tile staging stream per K-tile t: B0,B1,A0,A1 (j = 4t+kind).
// vmcnt(6) at each tile's phase 3 protects tile t+1; vmcnt(0) at t=14.
// ---------------------------------------------------------------------------
__global__ void __launch_bounds__(512) k_gemm_qkv8(
    const u16* __restrict__ xb, const u16* __restrict__ wb,
    u16* __restrict__ kb, u16* __restrict__ qb, u16* __restrict__ vb)
{
  extern __shared__ char smem[];
  u16* Ab = (u16*)smem;             // [2 buf][2 half][128*64]
  u16* Bb = (u16*)(smem + 65536);   // [2 buf][2 half][128*64]

  const int id = blockIdx.x;
  const int xcd = id & 7, loc = id >> 3;        // 384 blocks = 8 x 48
  const int mt = xcd * 4 + (loc & 3);           // each XCD owns 4 m-panels (2MB, L2-resident)
  const int nt = loc >> 2;                      // B-panel reused across 4 consecutive blocks
  const int m0 = mt * 256;
  const int n0g = nt * 256;                     // in [0,3072)

  const int tid = threadIdx.x;
  const int w = tid >> 6, l = tid & 63;
  const int wr = w >> 2, wc = w & 3;
  const int frow = l & 15, fko = l >> 4;
  const int bh = wc >> 1;                        // B half this wave reads
  const int srow = l >> 3;                       // staging row within 8-row chunk
  const int scol = ((l & 7) * 8) ^ ((l >> 5) << 4);  // pre-swizzled source col (st_16x32 inverse)

  f32x4 acc[8][4];
#pragma unroll
  for (int m_ = 0; m_ < 8; ++m_)
#pragma unroll
    for (int n_ = 0; n_ < 4; ++n_) acc[m_][n_] = (f32x4){0.f, 0.f, 0.f, 0.f};

  // stage one 128x64 half-tile: 8 waves x 2 gload_lds x 1KB, linear LDS dest,
  // swizzle realized by pre-permuted global source col (scol).
  auto stageA = [&](int t, int half) {
    const u16* g = xb + (size_t)(m0 + half * 128) * CDIM + t * 64 + scol;
    u16* lb = Ab + ((t & 1) * 2 + half) * 8192 + w * 1024;
    gload_lds16(g + (size_t)(w * 16 + srow) * CDIM, lb);
    gload_lds16(g + (size_t)(w * 16 + 8 + srow) * CDIM, lb + 512);
  };
  auto stageB = [&](int t, int half) {
    const u16* g = wb + (size_t)(n0g + half * 128) * CDIM + t * 64 + scol;
    u16* lb = Bb + ((t & 1) * 2 + half) * 8192 + w * 1024;
    gload_lds16(g + (size_t)(w * 16 + srow) * CDIM, lb);
    gload_lds16(g + (size_t)(w * 16 + 8 + srow) * CDIM, lb + 512);
  };
  auto stageH = [&](int j) {
    if (j >= 64) return;
    const int t = j >> 2, kind = j & 3;
    if (kind == 0) stageB(t, 0);
    else if (kind == 1) stageB(t, 1);
    else if (kind == 2) stageA(t, 0);
    else stageA(t, 1);
  };

#define SWZ(b_) ((b_) ^ ((((b_) >> 9) & 1) << 5))
#define AOFF(mf, ks) SWZ((((mf) * 16 + frow) * 128 + (ks) * 64 + fko * 16))
#define BOFF(nf, ks) SWZ((((wc & 1) * 64 + (nf) * 16 + frow) * 128 + (ks) * 64 + fko * 16))

#define PHASE(Q, JS, VM) do {                                                 \
    bf16x8 afr[2][2];                                                         \
    _Pragma("unroll") for (int mm = 0; mm < 2; ++mm)                          \
    _Pragma("unroll") for (int ks = 0; ks < 2; ++ks)                          \
        afr[mm][ks] = *(const bf16x8*)(Abase + AOFF(2 * (Q) + mm, ks));       \
    __builtin_amdgcn_sched_barrier(0);                                        \
    stageH(JS);                                                               \
    __builtin_amdgcn_s_barrier();                                             \
    __builtin_amdgcn_s_setprio(1);                                            \
    _Pragma("unroll") for (int ks = 0; ks < 2; ++ks)                          \
    _Pragma("unroll") for (int mm = 0; mm < 2; ++mm)                          \
    _Pragma("unroll") for (int nf = 0; nf < 4; ++nf)                          \
        acc[2 * (Q) + mm][nf] = __builtin_amdgcn_mfma_f32_16x16x32_bf16(      \
            afr[mm][ks], bfr[nf][ks], acc[2 * (Q) + mm][nf], 0, 0, 0);        \
    __builtin_amdgcn_s_setprio(0);                                            \
    if ((VM) == 6) asm volatile("s_waitcnt vmcnt(6)" ::: "memory");           \
    else if ((VM) == 0) asm volatile("s_waitcnt vmcnt(0)" ::: "memory");      \
    __builtin_amdgcn_s_barrier();                                             \
  } while (0)

#define KTILE(T, VM) do {                                                     \
    const char* Abase = (const char*)Ab + (((T) & 1) * 2 + wr) * 16384;       \
    const char* Bbase = (const char*)Bb + (((T) & 1) * 2 + bh) * 16384;       \
    bf16x8 bfr[4][2];                                                         \
    _Pragma("unroll") for (int nf = 0; nf < 4; ++nf)                          \
    _Pragma("unroll") for (int ks = 0; ks < 2; ++ks)                          \
        bfr[nf][ks] = *(const bf16x8*)(Bbase + BOFF(nf, ks));                 \
    PHASE(0, 4 * (T) + 7, -1);                                                \
    PHASE(1, 4 * (T) + 8, -1);                                                \
    PHASE(2, 4 * (T) + 9, -1);                                                \
    PHASE(3, 4 * (T) + 10, VM);                                               \
  } while (0)

  // prologue: stage H0..H6 (tile0 complete + 3 ahead), wait own first 8 loads
#pragma unroll
  for (int j = 0; j < 7; ++j) stageH(j);
  asm volatile("s_waitcnt vmcnt(6)" ::: "memory");
  __builtin_amdgcn_s_barrier();

#pragma unroll 1
  for (int i = 0; i < 7; ++i) { KTILE(2 * i, 6); KTILE(2 * i + 1, 6); }
  KTILE(14, 0);
  KTILE(15, -1);

#undef PHASE
#undef KTILE
#undef AOFF
#undef BOFF
#undef SWZ

  // epilogue: C write (z = which of K/Q/V this n-panel belongs to)
  const int z = n0g >> 10;
  u16* outp = (z == 0) ? kb : (z == 1) ? qb : vb;
  const float scale = (z == 1) ? 0.03125f : 1.0f;
  const int nc0 = (n0g & 1023) + wc * 64 + frow;
  const int r0 = m0 + wr * 128 + fko * 4;
#pragma unroll
  for (int mf = 0; mf < 8; ++mf)
#pragma unroll
    for (int nf = 0; nf < 4; ++nf) {
      const int r = r0 + mf * 16;
      const int c = nc0 + nf * 16;
#pragma unroll
      for (int j2 = 0; j2 < 4; ++j2)
        outp[(size_t)(r + j2) * CDIM + c] = f2bf(acc[mf][nf][j2] * scale);
    }
}

// ---------------------------------------------------------------------------
// V[2048][1024] -> Vt[1024][2048] per batch
__global__ void __launch_bounds__(256) k_transpose_v(const u16* __restrict__ vb,
                                                     u16* __restrict__ vt) {
  __shared__ u16 tile[32][33];
  const int b = blockIdx.z;
  const u16* V = vb + (size_t)b * TSEQ * CDIM;
  u16* Vt = vt + (size_t)b * CDIM * TSEQ;
  const int c0 = blockIdx.x * 32, r0 = blockIdx.y * 32;
  const int tx = threadIdx.x, ty = threadIdx.y;
#pragma unroll
  for (int j = 0; j < 4; ++j)
    tile[ty + j * 8][tx] = V[(size_t)(r0 + ty + j * 8) * CDIM + c0 + tx];
  __syncthreads();
#pragma unroll
  for (int j = 0; j < 4; ++j)
    Vt[(size_t)(c0 + ty + j * 8) * TSEQ + r0 + tx] = tile[tx][ty + j * 8];
}

// S = Q K^T then P_unnorm = exp(S) bf16 (max-free) + rowsum partials.
__global__ void __launch_bounds__(256) k_gemm_scores(
    const u16* __restrict__ qb, const u16* __restrict__ kb,
    u16* __restrict__ pb, float* __restrict__ rs)
{
  __shared__ u16 As[128 * 32], Bs[128 * 32];
  __shared__ float rowpart[128][2];
  const int id = blockIdx.x;
  const int sw = (id & 7) * 68 + (id >> 3);
  const int b = sw / 136;
  const int wq = sw - b * 136;
  int y = (int)((sqrtf(8.f * wq + 1.f) - 1.f) * 0.5f);
  while ((y + 1) * (y + 2) / 2 <= wq) ++y;
  while (y * (y + 1) / 2 > wq) --y;
  const int xt = wq - y * (y + 1) / 2;
  const int m0 = y * 128, n0 = xt * 128;

  const u16* A = qb + (size_t)b * TSEQ * CDIM;
  const u16* B = kb + (size_t)b * TSEQ * CDIM;
  u16* P = pb + (size_t)b * TSEQ * TSEQ;
  f32x4 acc[4][4];
  ACC_ZERO(acc);
  gemm_core_128(A, B, CDIM, CDIM, m0, n0, CDIM, As, Bs, acc);

  const int tid = threadIdx.x, w = tid >> 6, l = tid & 63;
  const int wr = w >> 1, wc = w & 1;
#pragma unroll
  for (int m = 0; m < 4; ++m) {
#pragma unroll
    for (int j = 0; j < 4; ++j) {
      const int rloc = wr * 64 + m * 16 + ((l >> 4) << 2) + j;
      const int rglob = m0 + rloc;
      float p4 = 0.f;
#pragma unroll
      for (int n = 0; n < 4; ++n) {
        const int c = n0 + wc * 64 + n * 16 + (l & 15);
        float e = (c <= rglob) ? __expf(acc[m][n][j]) : 0.f;
        p4 += e;
        P[(size_t)rglob * TSEQ + c] = f2bf(e);
      }
#pragma unroll
      for (int d = 1; d < 16; d <<= 1) p4 += __shfl_xor(p4, d);
      if ((l & 15) == 0) rowpart[rloc][wc] = p4;
    }
  }
  __syncthreads();
  if (tid < 128)
    rs[((size_t)b * 16 + xt) * TSEQ + m0 + tid] = rowpart[tid][0] + rowpart[tid][1];
}

// inv_rowsum[b][t] = 1 / sum_{x<=ytile} rs[b][x][t]
__global__ void __launch_bounds__(256) k_suminv(const float* __restrict__ rs,
                                                float* __restrict__ inv) {
  const int i = blockIdx.x * 256 + threadIdx.x;
  const int b = i >> 11, t = i & (TSEQ - 1), y = t >> 7;
  const float* p = rs + (size_t)b * 16 * TSEQ + t;
  float s = 0.f;
  for (int x = 0; x <= y; ++x) s += p[(size_t)x * TSEQ];
  inv[i] = 1.f / s;
}

// O = (P_unnorm @ V) * inv_rowsum ; causal K-extent per q-tile
__global__ void __launch_bounds__(256) k_gemm_pv(
    const u16* __restrict__ pb, const u16* __restrict__ vt,
    const float* __restrict__ inv, float* __restrict__ out)
{
  __shared__ u16 As[128 * 32], Bs[128 * 32];
  const int b = blockIdx.z;
  const u16* A = pb + (size_t)b * TSEQ * TSEQ;
  const u16* B = vt + (size_t)b * CDIM * TSEQ;
  float* O = out + (size_t)b * TSEQ * CDIM;
  const int m0 = blockIdx.y * 128, n0 = blockIdx.x * 128;
  const int kExt = (blockIdx.y + 1) * 128;
  f32x4 acc[4][4];
  ACC_ZERO(acc);
  gemm_core_128(A, B, TSEQ, TSEQ, m0, n0, kExt, As, Bs, acc);
  const int tid = threadIdx.x, w = tid >> 6, l = tid & 63;
  const int wr = w >> 1, wc = w & 1;
#pragma unroll
  for (int m = 0; m < 4; ++m) {
    const int r = m0 + wr * 64 + m * 16 + ((l >> 4) << 2);
    const float4 iv = *(const float4*)&inv[(size_t)b * TSEQ + r];
    const float ivj[4] = {iv.x, iv.y, iv.z, iv.w};
#pragma unroll
    for (int n = 0; n < 4; ++n) {
      const int c = n0 + wc * 64 + n * 16 + (l & 15);
#pragma unroll
      for (int j = 0; j < 4; ++j)
        O[(size_t)(r + j) * CDIM + c] = acc[m][n][j] * ivj[j];
    }
  }
}

// ---------------------------------------------------------------------------
extern "C" void kernel_launch(void* const* d_in, const int* in_sizes, int n_in,
                              void* d_out, int out_size, void* d_ws, size_t ws_size,
                              hipStream_t stream) {
  const float* x  = (const float*)d_in[0];
  const float* Wk = (const float*)d_in[1];
  const float* Wq = (const float*)d_in[2];
  const float* Wv = (const float*)d_in[3];
  float* out = (float*)d_out;

  const size_t M = (size_t)NBATCH * TSEQ;

  size_t off = 0;
  auto alloc = [&](size_t bytes) {
    void* p = (char*)d_ws + off;
    off += (bytes + 255) & ~(size_t)255;
    return p;
  };
  u16* xb = (u16*)alloc(M * CDIM * 2);
  u16* wb = (u16*)alloc(3ull * CDIM * CDIM * 2);
  u16* qb = (u16*)alloc(M * CDIM * 2);
  u16* kb = (u16*)alloc(M * CDIM * 2);
  u16* vb = (u16*)alloc(M * CDIM * 2);
  u16* pbuf = (u16*)alloc((size_t)NBATCH * TSEQ * TSEQ * 2);
  float* rs  = (float*)alloc((size_t)NBATCH * 16 * TSEQ * 4);
  float* inv = (float*)alloc(M * 4);
  if (off > ws_size) {
    fprintf(stderr, "kernel_launch: ws too small: need %zu, have %zu\n", off, ws_size);
    return;
  }
  u16* vt = xb;  // Vt overlay (x dead after QKV)

  const int NX4 = (NBATCH * TSEQ * CDIM) / 4;
  const int NW4 = (CDIM * CDIM) / 4;
  const int cvtBlocks = (NX4 + 3 * NW4) / 256;

  // allow 128KiB dynamic LDS (host-side attribute, capture-safe)
  static_cast<void>(hipFuncSetAttribute(
      reinterpret_cast<const void*>(k_gemm_qkv8),
      hipFuncAttributeMaxDynamicSharedMemorySize, 131072));

  k_cvt_all<<<cvtBlocks, 256, 0, stream>>>(x, Wk, Wq, Wv, xb, wb);
  k_gemm_qkv8<<<384, 512, 131072, stream>>>(xb, wb, kb, qb, vb);
  k_transpose_v<<<dim3(CDIM / 32, TSEQ / 32, NBATCH), dim3(32, 8), 0, stream>>>(vb, vt);
  k_gemm_scores<<<544, 256, 0, stream>>>(qb, kb, pbuf, rs);
  k_suminv<<<(int)(M / 256), 256, 0, stream>>>(rs, inv);
  k_gemm_pv<<<dim3(CDIM / 128, TSEQ / 128, NBATCH), 256, 0, stream>>>(pbuf, vt, inv, out);
}

// Round 5
// 169.253 us; speedup vs baseline: 1.0280x; 1.0280x over previous
//
#include <hip/hip_runtime.h>
#include <cstdio>
#include <cmath>

#define TSEQ 2048
#define CDIM 1024
#define NBATCH 4

typedef float f32x4 __attribute__((ext_vector_type(4)));
typedef __bf16 bf16x8 __attribute__((ext_vector_type(8)));
typedef unsigned short u16;

// f32 -> bf16 round-to-nearest-even
__device__ __forceinline__ u16 f2bf(float f) {
  unsigned u = __builtin_bit_cast(unsigned, f);
  unsigned r = (u + 0x7FFFu + ((u >> 16) & 1u)) >> 16;
  return (u16)r;
}

// async global->LDS, 16B per lane; lds base wave-uniform (HW adds lane*16)
__device__ __forceinline__ void gload_lds16(const void* g, void* l) {
  __builtin_amdgcn_global_load_lds(
      (__attribute__((address_space(1))) void*)g,
      (__attribute__((address_space(3))) void*)l, 16, 0, 0);
}

// ---------------------------------------------------------------------------
// legacy 128x128 core (scores/pv this round)
// ---------------------------------------------------------------------------
__device__ __forceinline__ void gemm_core_128(
    const u16* __restrict__ A, const u16* __restrict__ B,
    int lda, int ldb, int m0, int n0, int kEnd,
    u16* As, u16* Bs, f32x4 acc[4][4])
{
  const int tid = threadIdx.x;
  const int w = tid >> 6, l = tid & 63;
  const int wr = w >> 1, wc = w & 1;
  const int srow = l >> 2;
  const int scol = (l & 3) * 8;
  const int fr = l & 15;
  const int fk = (l >> 4) * 8;

  for (int k0 = 0; k0 < kEnd; k0 += 32) {
    const u16* ga = A + (size_t)(m0 + w * 16 + srow) * lda + k0 + scol;
    gload_lds16(ga, As + w * 16 * 32);
    gload_lds16(ga + (size_t)64 * lda, As + (64 + w * 16) * 32);
    const u16* gb = B + (size_t)(n0 + w * 16 + srow) * ldb + k0 + scol;
    gload_lds16(gb, Bs + w * 16 * 32);
    gload_lds16(gb + (size_t)64 * ldb, Bs + (64 + w * 16) * 32);
    __syncthreads();

    bf16x8 af[4], bfv[4];
#pragma unroll
    for (int i = 0; i < 4; ++i)
      af[i] = *reinterpret_cast<const bf16x8*>(As + (wr * 64 + i * 16 + fr) * 32 + fk);
#pragma unroll
    for (int i = 0; i < 4; ++i)
      bfv[i] = *reinterpret_cast<const bf16x8*>(Bs + (wc * 64 + i * 16 + fr) * 32 + fk);
#pragma unroll
    for (int m = 0; m < 4; ++m)
#pragma unroll
      for (int n = 0; n < 4; ++n)
        acc[m][n] = __builtin_amdgcn_mfma_f32_16x16x32_bf16(af[m], bfv[n], acc[m][n], 0, 0, 0);
    __syncthreads();
  }
}

#define ACC_ZERO(acc)                                   \
  _Pragma("unroll") for (int m_ = 0; m_ < 4; ++m_)      \
  _Pragma("unroll") for (int n_ = 0; n_ < 4; ++n_)      \
      acc[m_][n_] = (f32x4){0.f, 0.f, 0.f, 0.f};

// ---------------------------------------------------------------------------
// single cvt kernel for x, Wk, Wq, Wv
__global__ void __launch_bounds__(256) k_cvt_all(
    const float* __restrict__ x, const float* __restrict__ Wk,
    const float* __restrict__ Wq, const float* __restrict__ Wv,
    u16* __restrict__ xb, u16* __restrict__ wb)
{
  const int NX4 = (NBATCH * TSEQ * CDIM) / 4;
  const int NW4 = (CDIM * CDIM) / 4;
  int g = blockIdx.x * 256 + threadIdx.x;
  const float* src; u16* dst; int i;
  if (g < NX4) { src = x; dst = xb; i = g; }
  else {
    int g2 = g - NX4;
    int w = g2 / NW4; i = g2 - w * NW4;
    src = (w == 0) ? Wk : (w == 1) ? Wq : Wv;
    dst = wb + (size_t)w * CDIM * CDIM;
  }
  float4 v = ((const float4*)src)[i];
  ushort4 o;
  o.x = f2bf(v.x); o.y = f2bf(v.y); o.z = f2bf(v.z); o.w = f2bf(v.w);
  ((ushort4*)dst)[i] = o;
}

// ---------------------------------------------------------------------------
// 8-phase 256x256 QKV GEMM. A = xb [8192][1024], B = wb [3072][1024], K-major.
// 512 thr = 8 waves (2M x 4N), per-wave C = 128x64. BK=64, NT=16 K-tiles.
// LDS 128KiB: A/B x 2dbuf x 2half x [128 rows][64 cols] bf16 (128B rows).
// Swizzle (T2, full 3-bit): LDS[row][colblk ^ (row&7)] holds G[row][colblk]
// (colblk = 16B block, 8 per row). Write side: linear gload_lds dest +
// inverse-permuted global source col; read side: SWZ on ds_read address.
// Half-tile stream per K-tile t: B0,B1,A0,A1 (j = 4t+kind), vmcnt(6) at each
// tile's phase 3 (3 half-tiles in flight), vmcnt(0) at t=14.
// ---------------------------------------------------------------------------
__global__ void __launch_bounds__(512) k_gemm_qkv8(
    const u16* __restrict__ xb, const u16* __restrict__ wb,
    u16* __restrict__ kb, u16* __restrict__ qb, u16* __restrict__ vb)
{
  extern __shared__ char smem[];
  u16* Ab = (u16*)smem;             // [2 buf][2 half][128*64]
  u16* Bb = (u16*)(smem + 65536);   // [2 buf][2 half][128*64]

  const int id = blockIdx.x;
  const int xcd = id & 7, loc = id >> 3;        // 384 blocks = 8 x 48
  const int mt = xcd * 4 + (loc & 3);           // each XCD owns 4 m-panels
  const int nt = loc >> 2;
  const int m0 = mt * 256;
  const int n0g = nt * 256;                     // in [0,3072)

  const int tid = threadIdx.x;
  const int w = tid >> 6, l = tid & 63;
  const int wr = w >> 2, wc = w & 3;
  const int frow = l & 15, fko = l >> 4;
  const int bh = wc >> 1;                        // B half this wave reads
  const int srow = l >> 3;                       // staging row within 8-row chunk
  // inverse-swizzled source col (elements): colblk (l&7) ^ rowlow ((l>>3)&7)
  const int scol = ((l & 7) * 8) ^ (((l >> 3) & 7) << 3);

  f32x4 acc[8][4];
#pragma unroll
  for (int m_ = 0; m_ < 8; ++m_)
#pragma unroll
    for (int n_ = 0; n_ < 4; ++n_) acc[m_][n_] = (f32x4){0.f, 0.f, 0.f, 0.f};

  auto stageA = [&](int t, int half) {
    const u16* g = xb + (size_t)(m0 + half * 128) * CDIM + t * 64 + scol;
    u16* lb = Ab + ((t & 1) * 2 + half) * 8192 + w * 1024;
    gload_lds16(g + (size_t)(w * 16 + srow) * CDIM, lb);
    gload_lds16(g + (size_t)(w * 16 + 8 + srow) * CDIM, lb + 512);
  };
  auto stageB = [&](int t, int half) {
    const u16* g = wb + (size_t)(n0g + half * 128) * CDIM + t * 64 + scol;
    u16* lb = Bb + ((t & 1) * 2 + half) * 8192 + w * 1024;
    gload_lds16(g + (size_t)(w * 16 + srow) * CDIM, lb);
    gload_lds16(g + (size_t)(w * 16 + 8 + srow) * CDIM, lb + 512);
  };
  auto stageH = [&](int j) {
    if (j >= 64) return;
    const int t = j >> 2, kind = j & 3;
    if (kind == 0) stageB(t, 0);
    else if (kind == 1) stageB(t, 1);
    else if (kind == 2) stageA(t, 0);
    else stageA(t, 1);
  };

// full 3-bit XOR swizzle: byte ^= ((row&7)<<4), row = byte>>7 (128B rows)
#define SWZ(b_) ((b_) ^ (((((b_) >> 7) & 7)) << 4))
#define AOFF(mf, ks) SWZ((((mf) * 16 + frow) * 128 + (ks) * 64 + fko * 16))
#define BOFF(nf, ks) SWZ((((wc & 1) * 64 + (nf) * 16 + frow) * 128 + (ks) * 64 + fko * 16))

#define PHASE(Q, JS, VM) do {                                                 \
    bf16x8 afr[2][2];                                                         \
    _Pragma("unroll") for (int mm = 0; mm < 2; ++mm)                          \
    _Pragma("unroll") for (int ks = 0; ks < 2; ++ks)                          \
        afr[mm][ks] = *(const bf16x8*)(Abase + AOFF(2 * (Q) + mm, ks));       \
    __builtin_amdgcn_sched_barrier(0);                                        \
    stageH(JS);                                                               \
    __builtin_amdgcn_s_barrier();                                             \
    __builtin_amdgcn_s_setprio(1);                                            \
    _Pragma("unroll") for (int ks = 0; ks < 2; ++ks)                          \
    _Pragma("unroll") for (int mm = 0; mm < 2; ++mm)                          \
    _Pragma("unroll") for (int nf = 0; nf < 4; ++nf)                          \
        acc[2 * (Q) + mm][nf] = __builtin_amdgcn_mfma_f32_16x16x32_bf16(      \
            afr[mm][ks], bfr[nf][ks], acc[2 * (Q) + mm][nf], 0, 0, 0);        \
    __builtin_amdgcn_s_setprio(0);                                            \
    if ((VM) == 6) asm volatile("s_waitcnt vmcnt(6)" ::: "memory");           \
    else if ((VM) == 0) asm volatile("s_waitcnt vmcnt(0)" ::: "memory");      \
    __builtin_amdgcn_s_barrier();                                             \
  } while (0)

#define KTILE(T, VM) do {                                                     \
    const char* Abase = (const char*)Ab + (((T) & 1) * 2 + wr) * 16384;       \
    const char* Bbase = (const char*)Bb + (((T) & 1) * 2 + bh) * 16384;       \
    bf16x8 bfr[4][2];                                                         \
    _Pragma("unroll") for (int nf = 0; nf < 4; ++nf)                          \
    _Pragma("unroll") for (int ks = 0; ks < 2; ++ks)                          \
        bfr[nf][ks] = *(const bf16x8*)(Bbase + BOFF(nf, ks));                 \
    PHASE(0, 4 * (T) + 7, -1);                                                \
    PHASE(1, 4 * (T) + 8, -1);                                                \
    PHASE(2, 4 * (T) + 9, -1);                                                \
    PHASE(3, 4 * (T) + 10, VM);                                               \
  } while (0)

  // prologue: stage H0..H6 (tile0 complete + 3 ahead)
#pragma unroll
  for (int j = 0; j < 7; ++j) stageH(j);
  asm volatile("s_waitcnt vmcnt(6)" ::: "memory");
  __builtin_amdgcn_s_barrier();

#pragma unroll 1
  for (int i = 0; i < 7; ++i) { KTILE(2 * i, 6); KTILE(2 * i + 1, 6); }
  KTILE(14, 0);
  KTILE(15, -1);

#undef PHASE
#undef KTILE
#undef AOFF
#undef BOFF
#undef SWZ

  // epilogue: C write (z = which of K/Q/V this n-panel belongs to)
  const int z = n0g >> 10;
  u16* outp = (z == 0) ? kb : (z == 1) ? qb : vb;
  const float scale = (z == 1) ? 0.03125f : 1.0f;
  const int nc0 = (n0g & 1023) + wc * 64 + frow;
  const int r0 = m0 + wr * 128 + fko * 4;
#pragma unroll
  for (int mf = 0; mf < 8; ++mf)
#pragma unroll
    for (int nf = 0; nf < 4; ++nf) {
      const int r = r0 + mf * 16;
      const int c = nc0 + nf * 16;
#pragma unroll
      for (int j2 = 0; j2 < 4; ++j2)
        outp[(size_t)(r + j2) * CDIM + c] = f2bf(acc[mf][nf][j2] * scale);
    }
}

// ---------------------------------------------------------------------------
// V[2048][1024] -> Vt[1024][2048] per batch
__global__ void __launch_bounds__(256) k_transpose_v(const u16* __restrict__ vb,
                                                     u16* __restrict__ vt) {
  __shared__ u16 tile[32][33];
  const int b = blockIdx.z;
  const u16* V = vb + (size_t)b * TSEQ * CDIM;
  u16* Vt = vt + (size_t)b * CDIM * TSEQ;
  const int c0 = blockIdx.x * 32, r0 = blockIdx.y * 32;
  const int tx = threadIdx.x, ty = threadIdx.y;
#pragma unroll
  for (int j = 0; j < 4; ++j)
    tile[ty + j * 8][tx] = V[(size_t)(r0 + ty + j * 8) * CDIM + c0 + tx];
  __syncthreads();
#pragma unroll
  for (int j = 0; j < 4; ++j)
    Vt[(size_t)(c0 + ty + j * 8) * TSEQ + r0 + tx] = tile[tx][ty + j * 8];
}

// S = Q K^T then P_unnorm = exp(S) bf16 (max-free) + rowsum partials.
__global__ void __launch_bounds__(256) k_gemm_scores(
    const u16* __restrict__ qb, const u16* __restrict__ kb,
    u16* __restrict__ pb, float* __restrict__ rs)
{
  __shared__ u16 As[128 * 32], Bs[128 * 32];
  __shared__ float rowpart[128][2];
  const int id = blockIdx.x;
  const int sw = (id & 7) * 68 + (id >> 3);
  const int b = sw / 136;
  const int wq = sw - b * 136;
  int y = (int)((sqrtf(8.f * wq + 1.f) - 1.f) * 0.5f);
  while ((y + 1) * (y + 2) / 2 <= wq) ++y;
  while (y * (y + 1) / 2 > wq) --y;
  const int xt = wq - y * (y + 1) / 2;
  const int m0 = y * 128, n0 = xt * 128;

  const u16* A = qb + (size_t)b * TSEQ * CDIM;
  const u16* B = kb + (size_t)b * TSEQ * CDIM;
  u16* P = pb + (size_t)b * TSEQ * TSEQ;
  f32x4 acc[4][4];
  ACC_ZERO(acc);
  gemm_core_128(A, B, CDIM, CDIM, m0, n0, CDIM, As, Bs, acc);

  const int tid = threadIdx.x, w = tid >> 6, l = tid & 63;
  const int wr = w >> 1, wc = w & 1;
#pragma unroll
  for (int m = 0; m < 4; ++m) {
#pragma unroll
    for (int j = 0; j < 4; ++j) {
      const int rloc = wr * 64 + m * 16 + ((l >> 4) << 2) + j;
      const int rglob = m0 + rloc;
      float p4 = 0.f;
#pragma unroll
      for (int n = 0; n < 4; ++n) {
        const int c = n0 + wc * 64 + n * 16 + (l & 15);
        float e = (c <= rglob) ? __expf(acc[m][n][j]) : 0.f;
        p4 += e;
        P[(size_t)rglob * TSEQ + c] = f2bf(e);
      }
#pragma unroll
      for (int d = 1; d < 16; d <<= 1) p4 += __shfl_xor(p4, d);
      if ((l & 15) == 0) rowpart[rloc][wc] = p4;
    }
  }
  __syncthreads();
  if (tid < 128)
    rs[((size_t)b * 16 + xt) * TSEQ + m0 + tid] = rowpart[tid][0] + rowpart[tid][1];
}

// inv_rowsum[b][t] = 1 / sum_{x<=ytile} rs[b][x][t]
__global__ void __launch_bounds__(256) k_suminv(const float* __restrict__ rs,
                                                float* __restrict__ inv) {
  const int i = blockIdx.x * 256 + threadIdx.x;
  const int b = i >> 11, t = i & (TSEQ - 1), y = t >> 7;
  const float* p = rs + (size_t)b * 16 * TSEQ + t;
  float s = 0.f;
  for (int x = 0; x <= y; ++x) s += p[(size_t)x * TSEQ];
  inv[i] = 1.f / s;
}

// O = (P_unnorm @ V) * inv_rowsum ; causal K-extent per q-tile
__global__ void __launch_bounds__(256) k_gemm_pv(
    const u16* __restrict__ pb, const u16* __restrict__ vt,
    const float* __restrict__ inv, float* __restrict__ out)
{
  __shared__ u16 As[128 * 32], Bs[128 * 32];
  const int b = blockIdx.z;
  const u16* A = pb + (size_t)b * TSEQ * TSEQ;
  const u16* B = vt + (size_t)b * CDIM * TSEQ;
  float* O = out + (size_t)b * TSEQ * CDIM;
  const int m0 = blockIdx.y * 128, n0 = blockIdx.x * 128;
  const int kExt = (blockIdx.y + 1) * 128;
  f32x4 acc[4][4];
  ACC_ZERO(acc);
  gemm_core_128(A, B, TSEQ, TSEQ, m0, n0, kExt, As, Bs, acc);
  const int tid = threadIdx.x, w = tid >> 6, l = tid & 63;
  const int wr = w >> 1, wc = w & 1;
#pragma unroll
  for (int m = 0; m < 4; ++m) {
    const int r = m0 + wr * 64 + m * 16 + ((l >> 4) << 2);
    const float4 iv = *(const float4*)&inv[(size_t)b * TSEQ + r];
    const float ivj[4] = {iv.x, iv.y, iv.z, iv.w};
#pragma unroll
    for (int n = 0; n < 4; ++n) {
      const int c = n0 + wc * 64 + n * 16 + (l & 15);
#pragma unroll
      for (int j = 0; j < 4; ++j)
        O[(size_t)(r + j) * CDIM + c] = acc[m][n][j] * ivj[j];
    }
  }
}

// ---------------------------------------------------------------------------
extern "C" void kernel_launch(void* const* d_in, const int* in_sizes, int n_in,
                              void* d_out, int out_size, void* d_ws, size_t ws_size,
                              hipStream_t stream) {
  const float* x  = (const float*)d_in[0];
  const float* Wk = (const float*)d_in[1];
  const float* Wq = (const float*)d_in[2];
  const float* Wv = (const float*)d_in[3];
  float* out = (float*)d_out;

  const size_t M = (size_t)NBATCH * TSEQ;

  size_t off = 0;
  auto alloc = [&](size_t bytes) {
    void* p = (char*)d_ws + off;
    off += (bytes + 255) & ~(size_t)255;
    return p;
  };
  u16* xb = (u16*)alloc(M * CDIM * 2);
  u16* wb = (u16*)alloc(3ull * CDIM * CDIM * 2);
  u16* qb = (u16*)alloc(M * CDIM * 2);
  u16* kb = (u16*)alloc(M * CDIM * 2);
  u16* vb = (u16*)alloc(M * CDIM * 2);
  u16* pbuf = (u16*)alloc((size_t)NBATCH * TSEQ * TSEQ * 2);
  float* rs  = (float*)alloc((size_t)NBATCH * 16 * TSEQ * 4);
  float* inv = (float*)alloc(M * 4);
  if (off > ws_size) {
    fprintf(stderr, "kernel_launch: ws too small: need %zu, have %zu\n", off, ws_size);
    return;
  }
  u16* vt = xb;  // Vt overlay (x dead after QKV)

  const int NX4 = (NBATCH * TSEQ * CDIM) / 4;
  const int NW4 = (CDIM * CDIM) / 4;
  const int cvtBlocks = (NX4 + 3 * NW4) / 256;

  static_cast<void>(hipFuncSetAttribute(
      reinterpret_cast<const void*>(k_gemm_qkv8),
      hipFuncAttributeMaxDynamicSharedMemorySize, 131072));

  k_cvt_all<<<cvtBlocks, 256, 0, stream>>>(x, Wk, Wq, Wv, xb, wb);
  k_gemm_qkv8<<<384, 512, 131072, stream>>>(xb, wb, kb, qb, vb);
  k_transpose_v<<<dim3(CDIM / 32, TSEQ / 32, NBATCH), dim3(32, 8), 0, stream>>>(vb, vt);
  k_gemm_scores<<<544, 256, 0, stream>>>(qb, kb, pbuf, rs);
  k_suminv<<<(int)(M / 256), 256, 0, stream>>>(rs, inv);
  k_gemm_pv<<<dim3(CDIM / 128, TSEQ / 128, NBATCH), 256, 0, stream>>>(pbuf, vt, inv, out);
}